// Round 6
// baseline (5623.198 us; speedup 1.0000x reference)
//
#include <hip/hip_runtime.h>

#define Bq 128
#define Tq 256
#define Dq 512
#define Hq 1024
#define N4H 4096
#define KTOT 1536
#define LDW 1544   // LDS row stride in ushorts
#define NWG 128

typedef __attribute__((ext_vector_type(8))) short bf16x8;
typedef __attribute__((ext_vector_type(4))) float f32x4;
typedef __attribute__((ext_vector_type(2))) long long ll2;
typedef unsigned long long u64;

static __device__ __forceinline__ unsigned short f2bf(float x) {
    unsigned int u = __builtin_bit_cast(unsigned int, x);
    u = (u + 0x7FFFu + ((u >> 16) & 1u)) >> 16;
    return (unsigned short)u;
}
static __device__ __forceinline__ float bf2f(unsigned short h) {
    unsigned int u = ((unsigned int)h) << 16;
    return __builtin_bit_cast(float, u);
}
static __device__ __forceinline__ float sigm(float x) {
    return 1.f / (1.f + __expf(-x));
}
static __device__ __forceinline__ float tanh_f(float x) {
    return 2.f / (1.f + __expf(-2.f * x)) - 1.f;
}

// coherent (agent-scope, sc1) 16B h-load: two 8B relaxed atomic loads
static __device__ __forceinline__ bf16x8 ld_h16(const unsigned short* p) {
    u64 lo = __hip_atomic_load((const u64*)p, __ATOMIC_RELAXED, __HIP_MEMORY_SCOPE_AGENT);
    u64 hi = __hip_atomic_load((const u64*)(p + 4), __ATOMIC_RELAXED, __HIP_MEMORY_SCOPE_AGENT);
    ll2 v;
    v[0] = (long long)lo;
    v[1] = (long long)hi;
    return __builtin_bit_cast(bf16x8, v);
}

// ---- pack weights: Wp[n][k] bf16, n in [0,4096), k<512 from Kw, else Rw
__global__ __launch_bounds__(256) void pack_w(const float* __restrict__ Kw,
                                              const float* __restrict__ Rw,
                                              unsigned short* __restrict__ Wp) {
    __shared__ float tile[32][33];
    int nt = blockIdx.x * 32;
    int kt = blockIdx.y * 32;
    int tx = threadIdx.x, ty = threadIdx.y;  // 32 x 8
#pragma unroll
    for (int i = 0; i < 32; i += 8) {
        int k = kt + ty + i;
        int n = nt + tx;
        float v = (k < Dq) ? Kw[(size_t)k * N4H + n] : Rw[(size_t)(k - Dq) * N4H + n];
        tile[ty + i][tx] = v;
    }
    __syncthreads();
#pragma unroll
    for (int i = 0; i < 32; i += 8) {
        int n = nt + ty + i;
        int k = kt + tx;
        Wp[(size_t)n * KTOT + k] = f2bf(tile[tx][ty + i]);
    }
}

// ---- cast + transpose input to bf16 [T][B][D]
__global__ __launch_bounds__(256) void pack_x(const float* __restrict__ X,
                                              unsigned short* __restrict__ Xb) {
    int gid = blockIdx.x * 256 + threadIdx.x;  // 2,097,152 chunks of 8
    int dc = gid & 63;
    int t = (gid >> 6) & 255;
    int b = gid >> 14;
    const float* src = X + ((size_t)b * Tq + t) * Dq + dc * 8;
    float4 v0 = *(const float4*)src;
    float4 v1 = *(const float4*)(src + 4);
    bf16x8 r;
    r[0] = (short)f2bf(v0.x); r[1] = (short)f2bf(v0.y);
    r[2] = (short)f2bf(v0.z); r[3] = (short)f2bf(v0.w);
    r[4] = (short)f2bf(v1.x); r[5] = (short)f2bf(v1.y);
    r[6] = (short)f2bf(v1.z); r[7] = (short)f2bf(v1.w);
    *(bf16x8*)(Xb + ((size_t)t * Bq + b) * Dq + dc * 8) = r;
}

// ---- zero h buffer 0 + barrier state
__global__ __launch_bounds__(256) void init_ws(unsigned short* __restrict__ Hb,
                                               unsigned* __restrict__ bar) {
    int i = blockIdx.x * 256 + threadIdx.x;  // 131072
    Hb[i] = 0;
    if (i < 2048) bar[i] = 0;
}

// barrier word layout (u32 indices, 128B-separated counters):
//   xcd_cnt[x] @ x*32        (x in [0,16))
//   topo[x]    @ 512 + x*32
//   gbar       @ 1024
__global__ __launch_bounds__(256) void lstm_persist(
    const unsigned short* __restrict__ Wp,
    const unsigned short* __restrict__ Xb,
    const float* __restrict__ bias,
    unsigned short* __restrict__ Hb,
    const float* __restrict__ dw,
    const float* __restrict__ db,
    float* __restrict__ out,
    unsigned* __restrict__ bar) {
    extern __shared__ unsigned short Wl[];  // 32 * LDW ushorts = 98,816 B
    __shared__ float red[4];
    __shared__ int s_topo[3];  // myxcd, mytot, nxcd

    const int wg = blockIdx.x;
    const int hs0 = wg * 8;
    const int tid = threadIdx.x;
    const int wave = tid >> 6;
    const int lane = tid & 63;
    const int rowb = wave * 32;
    const int c16 = lane & 15;
    const int kg = lane >> 4;

    // ---- startup: discover physical XCD topology (pure relaxed atomics)
    if (tid == 0) {
        int xcd;
        asm volatile("s_getreg_b32 %0, hwreg(HW_REG_XCC_ID)" : "=s"(xcd));
        xcd &= 15;
        __hip_atomic_fetch_add(&bar[512 + xcd * 32], 1u, __ATOMIC_RELAXED, __HIP_MEMORY_SCOPE_AGENT);
        for (;;) {
            unsigned sum = 0;
            for (int i = 0; i < 16; ++i)
                sum += __hip_atomic_load(&bar[512 + i * 32], __ATOMIC_RELAXED, __HIP_MEMORY_SCOPE_AGENT);
            if (sum == NWG) break;
            __builtin_amdgcn_s_sleep(2);
        }
        int nx = 0, tot = 0;
        for (int i = 0; i < 16; ++i) {
            unsigned v = __hip_atomic_load(&bar[512 + i * 32], __ATOMIC_RELAXED, __HIP_MEMORY_SCOPE_AGENT);
            if (v) nx++;
            if (i == xcd) tot = (int)v;
        }
        s_topo[0] = xcd;
        s_topo[1] = tot;
        s_topo[2] = nx;
    }

    // load this wg's 32 weight columns into LDS (once)
    for (int c = tid; c < 32 * 192; c += 256) {
        int lc = c / 192;   // local col: q*8+u
        int pos = c % 192;  // bf16x8 chunk within row
        int q = lc >> 3, u = lc & 7;
        bf16x8 v = *(const bf16x8*)(Wp + (size_t)(q * Hq + hs0 + u) * KTOT + pos * 8);
        *(bf16x8*)(&Wl[lc * LDW + pos * 8]) = v;
    }

    const int col0 = (c16 >> 3) * Hq + hs0 + (c16 & 7);
    const int col1 = ((c16 >> 3) + 2) * Hq + hs0 + (c16 & 7);
    const float bias0 = bias[col0];
    const float bias1 = bias[col1];
    const bool hi = (c16 & 8) != 0;
    const int j = hs0 + (c16 & 7);
    const int arow0 = rowb + c16;
    const int arow1 = arow0 + 16;
    const int wl0 = c16 * LDW + kg * 8;
    const int wl1 = (16 + c16) * LDW + kg * 8;

    float creg[8];
#pragma unroll
    for (int i = 0; i < 8; ++i) creg[i] = 0.f;

    __syncthreads();
    const int myxcd = s_topo[0];
    const unsigned mytot = (unsigned)s_topo[1];
    const unsigned nxcd = (unsigned)s_topo[2];

    // x-part accumulators (one step ahead); x reads are NORMAL loads (L2-cached,
    // never invalidated in this scheme)
    f32x4 xa00 = {0.f, 0.f, 0.f, 0.f};
    f32x4 xa01 = {0.f, 0.f, 0.f, 0.f};
    f32x4 xa10 = {0.f, 0.f, 0.f, 0.f};
    f32x4 xa11 = {0.f, 0.f, 0.f, 0.f};
    {
        const unsigned short* xr0 = Xb + ((size_t)arow0) * Dq + kg * 8;
        const unsigned short* xr1 = Xb + ((size_t)arow1) * Dq + kg * 8;
#pragma unroll 4
        for (int kc = 0; kc < 16; ++kc) {
            bf16x8 a0 = *(const bf16x8*)(xr0 + kc * 32);
            bf16x8 a1 = *(const bf16x8*)(xr1 + kc * 32);
            bf16x8 b0 = *(const bf16x8*)(&Wl[wl0 + kc * 32]);
            bf16x8 b1 = *(const bf16x8*)(&Wl[wl1 + kc * 32]);
            xa00 = __builtin_amdgcn_mfma_f32_16x16x32_bf16(a0, b0, xa00, 0, 0, 0);
            xa01 = __builtin_amdgcn_mfma_f32_16x16x32_bf16(a0, b1, xa01, 0, 0, 0);
            xa10 = __builtin_amdgcn_mfma_f32_16x16x32_bf16(a1, b0, xa10, 0, 0, 0);
            xa11 = __builtin_amdgcn_mfma_f32_16x16x32_bf16(a1, b1, xa11, 0, 0, 0);
        }
    }

    for (int t = 0; t < Tq; ++t) {
        const unsigned short* Hcur = Hb + (size_t)(t & 1) * (Bq * Hq);
        unsigned short* Hnxt = Hb + (size_t)((t + 1) & 1) * (Bq * Hq);

        const unsigned short* hr0 = Hcur + (size_t)arow0 * Hq + kg * 8;
        const unsigned short* hr1 = Hcur + (size_t)arow1 * Hq + kg * 8;

        f32x4 acc00 = xa00, acc01 = xa01, acc10 = xa10, acc11 = xa11;

        // h-part GEMM: A-fragments via coherent (sc1) loads from the IF$
#pragma unroll 4
        for (int kc = 0; kc < 32; ++kc) {
            bf16x8 a0 = ld_h16(hr0 + kc * 32);
            bf16x8 a1 = ld_h16(hr1 + kc * 32);
            bf16x8 b0 = *(const bf16x8*)(&Wl[wl0 + 512 + kc * 32]);
            bf16x8 b1 = *(const bf16x8*)(&Wl[wl1 + 512 + kc * 32]);
            acc00 = __builtin_amdgcn_mfma_f32_16x16x32_bf16(a0, b0, acc00, 0, 0, 0);
            acc01 = __builtin_amdgcn_mfma_f32_16x16x32_bf16(a0, b1, acc01, 0, 0, 0);
            acc10 = __builtin_amdgcn_mfma_f32_16x16x32_bf16(a1, b0, acc10, 0, 0, 0);
            acc11 = __builtin_amdgcn_mfma_f32_16x16x32_bf16(a1, b1, acc11, 0, 0, 0);
        }

#pragma unroll
        for (int m = 0; m < 2; ++m) {
            f32x4 z0 = m ? acc10 : acc00;
            f32x4 z1 = m ? acc11 : acc01;
#pragma unroll
            for (int r = 0; r < 4; ++r) {
                float za = z0[r] + bias0;
                float zb = z1[r] + bias1;
                float pa = __shfl_xor(za, 8, 64);
                float pb = __shfl_xor(zb, 8, 64);
                float zi = hi ? pa : za;
                float zf = hi ? za : pa;
                float zg = hi ? pb : zb;
                float zo = hi ? zb : pb;
                float gi = sigm(zi);
                float gf = sigm(zf);
                float go = sigm(zo);
                float gg = tanh_f(zg);
                float cn = gf * creg[m * 4 + r] + gi * gg;
                creg[m * 4 + r] = cn;
                float hn = go * tanh_f(cn);
                // pair (j even, j odd) across lanes c16=2k,2k+1 -> one 4B coherent store
                unsigned hb16 = (unsigned)f2bf(hn);
                unsigned pv = (unsigned)__shfl_xor((int)hb16, 1, 64);
                unsigned word = (c16 & 1) ? ((pv & 0xffffu) | (hb16 << 16))
                                          : ((hb16 & 0xffffu) | (pv << 16));
                if (!hi && (c16 & 1) == m) {
                    int b = rowb + m * 16 + kg * 4 + r;
                    __hip_atomic_store((unsigned*)(Hnxt + (size_t)b * Hq + (j & ~1)), word,
                                       __ATOMIC_RELAXED, __HIP_MEMORY_SCOPE_AGENT);
                }
            }
        }

        // ---- arrive: __syncthreads drains vmcnt (sc1 store acks from IF$),
        // then per-XCD counter; last arriver on XCD bumps the global counter.
        // NO fences anywhere.
        __syncthreads();
        if (tid == 0) {
            unsigned old = __hip_atomic_fetch_add(&bar[myxcd * 32], 1u,
                                                  __ATOMIC_RELAXED, __HIP_MEMORY_SCOPE_AGENT);
            if (old == (unsigned)(t + 1) * mytot - 1u) {
                __hip_atomic_fetch_add(&bar[1024], 1u,
                                       __ATOMIC_RELAXED, __HIP_MEMORY_SCOPE_AGENT);
            }
        }

        // ---- overlap: x-part GEMM for step t+1 (L2-warm) while others arrive
        xa00 = (f32x4){0.f, 0.f, 0.f, 0.f};
        xa01 = (f32x4){0.f, 0.f, 0.f, 0.f};
        xa10 = (f32x4){0.f, 0.f, 0.f, 0.f};
        xa11 = (f32x4){0.f, 0.f, 0.f, 0.f};
        if (t + 1 < Tq) {
            const unsigned short* xr0 = Xb + ((size_t)(t + 1) * Bq + arow0) * Dq + kg * 8;
            const unsigned short* xr1 = Xb + ((size_t)(t + 1) * Bq + arow1) * Dq + kg * 8;
#pragma unroll 4
            for (int kc = 0; kc < 16; ++kc) {
                bf16x8 a0 = *(const bf16x8*)(xr0 + kc * 32);
                bf16x8 a1 = *(const bf16x8*)(xr1 + kc * 32);
                bf16x8 b0 = *(const bf16x8*)(&Wl[wl0 + kc * 32]);
                bf16x8 b1 = *(const bf16x8*)(&Wl[wl1 + kc * 32]);
                xa00 = __builtin_amdgcn_mfma_f32_16x16x32_bf16(a0, b0, xa00, 0, 0, 0);
                xa01 = __builtin_amdgcn_mfma_f32_16x16x32_bf16(a0, b1, xa01, 0, 0, 0);
                xa10 = __builtin_amdgcn_mfma_f32_16x16x32_bf16(a1, b0, xa10, 0, 0, 0);
                xa11 = __builtin_amdgcn_mfma_f32_16x16x32_bf16(a1, b1, xa11, 0, 0, 0);
            }
        }

        // ---- wait: relaxed polls only (h data rides the coherence point, not L2)
        if (tid == 0) {
            const unsigned target = (unsigned)(t + 1) * nxcd;
            while (__hip_atomic_load(&bar[1024], __ATOMIC_RELAXED, __HIP_MEMORY_SCOPE_AGENT) < target) {
                __builtin_amdgcn_s_sleep(2);
            }
        }
        __syncthreads();
    }

    // dense head: wg handles batch row b = wg; final h is in buffer 0 (t=256 even).
    // h must be read coherently (local L2 may hold stale zero-init lines).
    {
        const unsigned short* hl = Hb + (size_t)wg * Hq;
        float s = 0.f;
        for (int jj = tid; jj < Hq / 2; jj += 256) {
            unsigned w = __hip_atomic_load((const unsigned*)(hl + jj * 2),
                                           __ATOMIC_RELAXED, __HIP_MEMORY_SCOPE_AGENT);
            s += bf2f((unsigned short)(w & 0xffffu)) * dw[jj * 2] +
                 bf2f((unsigned short)(w >> 16)) * dw[jj * 2 + 1];
        }
#pragma unroll
        for (int off = 32; off > 0; off >>= 1) s += __shfl_down(s, off, 64);
        if (lane == 0) red[wave] = s;
        __syncthreads();
        if (tid == 0) out[wg] = 1.f / (1.f + __expf(-(red[0] + red[1] + red[2] + red[3] + db[0])));
    }
}

extern "C" void kernel_launch(void* const* d_in, const int* in_sizes, int n_in,
                              void* d_out, int out_size, void* d_ws, size_t ws_size,
                              hipStream_t stream) {
    const float* X = (const float*)d_in[0];
    const float* Kw = (const float*)d_in[1];
    const float* Rw = (const float*)d_in[2];
    const float* bias = (const float*)d_in[3];
    const float* dw = (const float*)d_in[4];
    const float* db = (const float*)d_in[5];
    float* out = (float*)d_out;
    char* ws = (char*)d_ws;

    // workspace layout:
    //   Wp  bf16 [4096][1536]     @ 0          (12,582,912)
    //   Xb  bf16 [256][128][512]  @ 12,582,912 (33,554,432)   [T][B][D]
    //   Hb  bf16 [2][128][1024]   @ 46,137,344 (524,288)
    //   bar u32  [2048]           @ 46,661,632 (8,192)
    unsigned short* Wp = (unsigned short*)(ws);
    unsigned short* Xb = (unsigned short*)(ws + 12582912);
    unsigned short* Hb = (unsigned short*)(ws + 46137344);
    unsigned* bar = (unsigned*)(ws + 46661632);

    pack_w<<<dim3(128, 48), dim3(32, 8), 0, stream>>>(Kw, Rw, Wp);
    pack_x<<<8192, 256, 0, stream>>>(X, Xb);
    init_ws<<<512, 256, 0, stream>>>(Hb, bar);

    size_t lds_bytes = (size_t)32 * LDW * sizeof(unsigned short);  // 98,816
    lstm_persist<<<NWG, 256, lds_bytes, stream>>>(Wp, Xb, bias, Hb, dw, db, out, bar);
}

// Round 7
// 4777.444 us; speedup vs baseline: 1.1770x; 1.1770x over previous
//
#include <hip/hip_runtime.h>

#define Bq 128
#define Tq 256
#define Dq 512
#define Hq 1024
#define N4H 4096
#define KTOT 1536
#define LDW 1544   // LDS row stride in ushorts
#define NWG 128

typedef __attribute__((ext_vector_type(8))) short bf16x8;
typedef __attribute__((ext_vector_type(4))) float f32x4;

static __device__ __forceinline__ unsigned short f2bf(float x) {
    unsigned int u = __builtin_bit_cast(unsigned int, x);
    u = (u + 0x7FFFu + ((u >> 16) & 1u)) >> 16;
    return (unsigned short)u;
}
static __device__ __forceinline__ float bf2f(unsigned short h) {
    unsigned int u = ((unsigned int)h) << 16;
    return __builtin_bit_cast(float, u);
}
static __device__ __forceinline__ float sigm(float x) {
    return 1.f / (1.f + __expf(-x));
}
static __device__ __forceinline__ float tanh_f(float x) {
    return 2.f / (1.f + __expf(-2.f * x)) - 1.f;
}

// ---- pack weights: Wp[n][k] bf16, n in [0,4096), k<512 from Kw, else Rw
__global__ __launch_bounds__(256) void pack_w(const float* __restrict__ Kw,
                                              const float* __restrict__ Rw,
                                              unsigned short* __restrict__ Wp) {
    __shared__ float tile[32][33];
    int nt = blockIdx.x * 32;
    int kt = blockIdx.y * 32;
    int tx = threadIdx.x, ty = threadIdx.y;  // 32 x 8
#pragma unroll
    for (int i = 0; i < 32; i += 8) {
        int k = kt + ty + i;
        int n = nt + tx;
        float v = (k < Dq) ? Kw[(size_t)k * N4H + n] : Rw[(size_t)(k - Dq) * N4H + n];
        tile[ty + i][tx] = v;
    }
    __syncthreads();
#pragma unroll
    for (int i = 0; i < 32; i += 8) {
        int n = nt + ty + i;
        int k = kt + tx;
        Wp[(size_t)n * KTOT + k] = f2bf(tile[tx][ty + i]);
    }
}

// ---- cast + transpose input to bf16 [T][B][D]
__global__ __launch_bounds__(256) void pack_x(const float* __restrict__ X,
                                              unsigned short* __restrict__ Xb) {
    int gid = blockIdx.x * 256 + threadIdx.x;  // 2,097,152 chunks of 8
    int dc = gid & 63;
    int t = (gid >> 6) & 255;
    int b = gid >> 14;
    const float* src = X + ((size_t)b * Tq + t) * Dq + dc * 8;
    float4 v0 = *(const float4*)src;
    float4 v1 = *(const float4*)(src + 4);
    bf16x8 r;
    r[0] = (short)f2bf(v0.x); r[1] = (short)f2bf(v0.y);
    r[2] = (short)f2bf(v0.z); r[3] = (short)f2bf(v0.w);
    r[4] = (short)f2bf(v1.x); r[5] = (short)f2bf(v1.y);
    r[6] = (short)f2bf(v1.z); r[7] = (short)f2bf(v1.w);
    *(bf16x8*)(Xb + ((size_t)t * Bq + b) * Dq + dc * 8) = r;
}

// ---- zero h buffer 0 + barrier state
__global__ __launch_bounds__(256) void init_ws(unsigned short* __restrict__ Hb,
                                               unsigned* __restrict__ bar) {
    int i = blockIdx.x * 256 + threadIdx.x;  // 131072
    Hb[i] = 0;
    if (i < 2048) bar[i] = 0;
}

// barrier word layout (u32 indices, 128B-separated lines):
//   xcd_cnt[x] @ x*32          (x in [0,16))   - arrival counters, adds only
//   topo[x]    @ 512 + x*32                    - startup registration
//   gbar       @ 1024                          - global counter, adds only (8/step)
//   xflag[x]   @ 1280 + x*32                   - step flags, <=16 pollers each
__global__ __launch_bounds__(256) void lstm_persist(
    const unsigned short* __restrict__ Wp,
    const unsigned short* __restrict__ Xb,
    const float* __restrict__ bias,
    unsigned short* __restrict__ Hb,
    const float* __restrict__ dw,
    const float* __restrict__ db,
    float* __restrict__ out,
    unsigned* __restrict__ bar) {
    extern __shared__ unsigned short Wl[];  // 32 * LDW ushorts = 98,816 B
    __shared__ float red[4];
    __shared__ int s_topo[3];  // myxcd, mytot, nxcd

    const int wg = blockIdx.x;
    const int hs0 = wg * 8;
    const int tid = threadIdx.x;
    const int wave = tid >> 6;
    const int lane = tid & 63;
    const int rowb = wave * 32;
    const int c16 = lane & 15;
    const int kg = lane >> 4;

    // ---- startup: discover physical XCD topology (pure relaxed atomics)
    if (tid == 0) {
        int xcd;
        asm volatile("s_getreg_b32 %0, hwreg(HW_REG_XCC_ID)" : "=s"(xcd));
        xcd &= 15;
        __hip_atomic_fetch_add(&bar[512 + xcd * 32], 1u, __ATOMIC_RELAXED, __HIP_MEMORY_SCOPE_AGENT);
        for (;;) {
            unsigned sum = 0;
            for (int i = 0; i < 16; ++i)
                sum += __hip_atomic_load(&bar[512 + i * 32], __ATOMIC_RELAXED, __HIP_MEMORY_SCOPE_AGENT);
            if (sum == NWG) break;
            __builtin_amdgcn_s_sleep(2);
        }
        int nx = 0, tot = 0;
        for (int i = 0; i < 16; ++i) {
            unsigned v = __hip_atomic_load(&bar[512 + i * 32], __ATOMIC_RELAXED, __HIP_MEMORY_SCOPE_AGENT);
            if (v) nx++;
            if (i == xcd) tot = (int)v;
        }
        s_topo[0] = xcd;
        s_topo[1] = tot;
        s_topo[2] = nx;
    }

    // load this wg's 32 weight columns into LDS (once)
    for (int c = tid; c < 32 * 192; c += 256) {
        int lc = c / 192;   // local col: q*8+u
        int pos = c % 192;  // bf16x8 chunk within row
        int q = lc >> 3, u = lc & 7;
        bf16x8 v = *(const bf16x8*)(Wp + (size_t)(q * Hq + hs0 + u) * KTOT + pos * 8);
        *(bf16x8*)(&Wl[lc * LDW + pos * 8]) = v;
    }

    const int col0 = (c16 >> 3) * Hq + hs0 + (c16 & 7);
    const int col1 = ((c16 >> 3) + 2) * Hq + hs0 + (c16 & 7);
    const float bias0 = bias[col0];
    const float bias1 = bias[col1];
    const bool hi = (c16 & 8) != 0;
    const int j = hs0 + (c16 & 7);
    const int arow0 = rowb + c16;
    const int arow1 = arow0 + 16;
    const int wl0 = c16 * LDW + kg * 8;
    const int wl1 = (16 + c16) * LDW + kg * 8;

    float creg[8];
#pragma unroll
    for (int i = 0; i < 8; ++i) creg[i] = 0.f;

    __syncthreads();
    const int myxcd = s_topo[0];
    const unsigned mytot = (unsigned)s_topo[1];
    const unsigned nxcd = (unsigned)s_topo[2];

    // x-part accumulators (one step ahead)
    f32x4 xa00 = {0.f, 0.f, 0.f, 0.f};
    f32x4 xa01 = {0.f, 0.f, 0.f, 0.f};
    f32x4 xa10 = {0.f, 0.f, 0.f, 0.f};
    f32x4 xa11 = {0.f, 0.f, 0.f, 0.f};
    {
        const unsigned short* xr0 = Xb + ((size_t)arow0) * Dq + kg * 8;
        const unsigned short* xr1 = Xb + ((size_t)arow1) * Dq + kg * 8;
#pragma unroll 4
        for (int kc = 0; kc < 16; ++kc) {
            bf16x8 a0 = *(const bf16x8*)(xr0 + kc * 32);
            bf16x8 a1 = *(const bf16x8*)(xr1 + kc * 32);
            bf16x8 b0 = *(const bf16x8*)(&Wl[wl0 + kc * 32]);
            bf16x8 b1 = *(const bf16x8*)(&Wl[wl1 + kc * 32]);
            xa00 = __builtin_amdgcn_mfma_f32_16x16x32_bf16(a0, b0, xa00, 0, 0, 0);
            xa01 = __builtin_amdgcn_mfma_f32_16x16x32_bf16(a0, b1, xa01, 0, 0, 0);
            xa10 = __builtin_amdgcn_mfma_f32_16x16x32_bf16(a1, b0, xa10, 0, 0, 0);
            xa11 = __builtin_amdgcn_mfma_f32_16x16x32_bf16(a1, b1, xa11, 0, 0, 0);
        }
    }

    for (int t = 0; t < Tq; ++t) {
        const unsigned short* Hcur = Hb + (size_t)(t & 1) * (Bq * Hq);
        unsigned short* Hnxt = Hb + (size_t)((t + 1) & 1) * (Bq * Hq);

        const unsigned short* hr0 = Hcur + (size_t)arow0 * Hq + kg * 8;
        const unsigned short* hr1 = Hcur + (size_t)arow1 * Hq + kg * 8;

        f32x4 acc00 = xa00, acc01 = xa01, acc10 = xa10, acc11 = xa11;

#pragma unroll 4
        for (int kc = 0; kc < 32; ++kc) {
            bf16x8 a0 = *(const bf16x8*)(hr0 + kc * 32);
            bf16x8 a1 = *(const bf16x8*)(hr1 + kc * 32);
            bf16x8 b0 = *(const bf16x8*)(&Wl[wl0 + 512 + kc * 32]);
            bf16x8 b1 = *(const bf16x8*)(&Wl[wl1 + 512 + kc * 32]);
            acc00 = __builtin_amdgcn_mfma_f32_16x16x32_bf16(a0, b0, acc00, 0, 0, 0);
            acc01 = __builtin_amdgcn_mfma_f32_16x16x32_bf16(a0, b1, acc01, 0, 0, 0);
            acc10 = __builtin_amdgcn_mfma_f32_16x16x32_bf16(a1, b0, acc10, 0, 0, 0);
            acc11 = __builtin_amdgcn_mfma_f32_16x16x32_bf16(a1, b1, acc11, 0, 0, 0);
        }

#pragma unroll
        for (int m = 0; m < 2; ++m) {
            f32x4 z0 = m ? acc10 : acc00;
            f32x4 z1 = m ? acc11 : acc01;
#pragma unroll
            for (int r = 0; r < 4; ++r) {
                float za = z0[r] + bias0;
                float zb = z1[r] + bias1;
                float pa = __shfl_xor(za, 8, 64);
                float pb = __shfl_xor(zb, 8, 64);
                float zi = hi ? pa : za;
                float zf = hi ? za : pa;
                float zg = hi ? pb : zb;
                float zo = hi ? zb : pb;
                float gi = sigm(zi);
                float gf = sigm(zf);
                float go = sigm(zo);
                float gg = tanh_f(zg);
                float cn = gf * creg[m * 4 + r] + gi * gg;
                creg[m * 4 + r] = cn;
                float hn = go * tanh_f(cn);
                if (!hi) {
                    int b = rowb + m * 16 + kg * 4 + r;
                    Hnxt[(size_t)b * Hq + j] = f2bf(hn);
                }
            }
        }

        // ---- arrive: __syncthreads drains each wave's stores into local L2.
        // Per-XCD arrival counter (adds only). Last arriver on XCD: 1 release
        // wbl2 + global add. Last arriver globally (detected via RETURN VALUE,
        // nobody polls gbar): fan-out stores to 16 per-XCD flag lines.
        __syncthreads();
        if (tid == 0) {
            unsigned old = __hip_atomic_fetch_add(&bar[myxcd * 32], 1u,
                                                  __ATOMIC_RELAXED, __HIP_MEMORY_SCOPE_AGENT);
            if (old == (unsigned)(t + 1) * mytot - 1u) {
                __builtin_amdgcn_fence(__ATOMIC_RELEASE, "agent");  // 1 wbl2 per XCD per step
                unsigned gold = __hip_atomic_fetch_add(&bar[1024], 1u,
                                                       __ATOMIC_RELAXED, __HIP_MEMORY_SCOPE_AGENT);
                if (gold == (unsigned)(t + 1) * nxcd - 1u) {
#pragma unroll
                    for (int x = 0; x < 16; ++x)
                        __hip_atomic_store(&bar[1280 + x * 32], (unsigned)(t + 1),
                                           __ATOMIC_RELAXED, __HIP_MEMORY_SCOPE_AGENT);
                }
            }
        }

        // ---- overlap: x-part GEMM for step t+1 while others arrive
        xa00 = (f32x4){0.f, 0.f, 0.f, 0.f};
        xa01 = (f32x4){0.f, 0.f, 0.f, 0.f};
        xa10 = (f32x4){0.f, 0.f, 0.f, 0.f};
        xa11 = (f32x4){0.f, 0.f, 0.f, 0.f};
        if (t + 1 < Tq) {
            const unsigned short* xr0 = Xb + ((size_t)(t + 1) * Bq + arow0) * Dq + kg * 8;
            const unsigned short* xr1 = Xb + ((size_t)(t + 1) * Bq + arow1) * Dq + kg * 8;
#pragma unroll 4
            for (int kc = 0; kc < 16; ++kc) {
                bf16x8 a0 = *(const bf16x8*)(xr0 + kc * 32);
                bf16x8 a1 = *(const bf16x8*)(xr1 + kc * 32);
                bf16x8 b0 = *(const bf16x8*)(&Wl[wl0 + kc * 32]);
                bf16x8 b1 = *(const bf16x8*)(&Wl[wl1 + kc * 32]);
                xa00 = __builtin_amdgcn_mfma_f32_16x16x32_bf16(a0, b0, xa00, 0, 0, 0);
                xa01 = __builtin_amdgcn_mfma_f32_16x16x32_bf16(a0, b1, xa01, 0, 0, 0);
                xa10 = __builtin_amdgcn_mfma_f32_16x16x32_bf16(a1, b0, xa10, 0, 0, 0);
                xa11 = __builtin_amdgcn_mfma_f32_16x16x32_bf16(a1, b1, xa11, 0, 0, 0);
            }
        }

        // ---- wait: poll ONLY this XCD's flag line (<=16 pollers/line), then
        // one acquire inv per wg. Compiler fence stops h-load hoisting.
        if (tid == 0) {
            while (__hip_atomic_load(&bar[1280 + myxcd * 32], __ATOMIC_RELAXED,
                                     __HIP_MEMORY_SCOPE_AGENT) < (unsigned)(t + 1)) {
                __builtin_amdgcn_s_sleep(4);
            }
            asm volatile("" ::: "memory");
            __builtin_amdgcn_fence(__ATOMIC_ACQUIRE, "agent");
        }
        __syncthreads();
    }

    // dense head: wg handles batch row b = wg; final h is in buffer 0 (t=256 even)
    {
        const unsigned short* hl = Hb + (size_t)wg * Hq;
        float s = 0.f;
        for (int jj = tid; jj < Hq; jj += 256) s += bf2f(hl[jj]) * dw[jj];
#pragma unroll
        for (int off = 32; off > 0; off >>= 1) s += __shfl_down(s, off, 64);
        if (lane == 0) red[wave] = s;
        __syncthreads();
        if (tid == 0) out[wg] = 1.f / (1.f + __expf(-(red[0] + red[1] + red[2] + red[3] + db[0])));
    }
}

extern "C" void kernel_launch(void* const* d_in, const int* in_sizes, int n_in,
                              void* d_out, int out_size, void* d_ws, size_t ws_size,
                              hipStream_t stream) {
    const float* X = (const float*)d_in[0];
    const float* Kw = (const float*)d_in[1];
    const float* Rw = (const float*)d_in[2];
    const float* bias = (const float*)d_in[3];
    const float* dw = (const float*)d_in[4];
    const float* db = (const float*)d_in[5];
    float* out = (float*)d_out;
    char* ws = (char*)d_ws;

    // workspace layout:
    //   Wp  bf16 [4096][1536]     @ 0          (12,582,912)
    //   Xb  bf16 [256][128][512]  @ 12,582,912 (33,554,432)   [T][B][D]
    //   Hb  bf16 [2][128][1024]   @ 46,137,344 (524,288)
    //   bar u32  [2048]           @ 46,661,632 (8,192)
    unsigned short* Wp = (unsigned short*)(ws);
    unsigned short* Xb = (unsigned short*)(ws + 12582912);
    unsigned short* Hb = (unsigned short*)(ws + 46137344);
    unsigned* bar = (unsigned*)(ws + 46661632);

    pack_w<<<dim3(128, 48), dim3(32, 8), 0, stream>>>(Kw, Rw, Wp);
    pack_x<<<8192, 256, 0, stream>>>(X, Xb);
    init_ws<<<512, 256, 0, stream>>>(Hb, bar);

    size_t lds_bytes = (size_t)32 * LDW * sizeof(unsigned short);  // 98,816
    lstm_persist<<<NWG, 256, lds_bytes, stream>>>(Wp, Xb, bias, Hb, dw, db, out, bar);
}

// Round 8
// 4086.308 us; speedup vs baseline: 1.3761x; 1.1691x over previous
//
#include <hip/hip_runtime.h>

#define Bq 128
#define Tq 256
#define Dq 512
#define Hq 1024
#define N4H 4096
#define KTOT 1536
#define LDW 1544   // LDS row stride in ushorts
#define NWG 128
#define NTHR 1024

typedef __attribute__((ext_vector_type(8))) short bf16x8;
typedef __attribute__((ext_vector_type(4))) float f32x4;

static __device__ __forceinline__ unsigned short f2bf(float x) {
    unsigned int u = __builtin_bit_cast(unsigned int, x);
    u = (u + 0x7FFFu + ((u >> 16) & 1u)) >> 16;
    return (unsigned short)u;
}
static __device__ __forceinline__ float bf2f(unsigned short h) {
    unsigned int u = ((unsigned int)h) << 16;
    return __builtin_bit_cast(float, u);
}
static __device__ __forceinline__ float sigm(float x) {
    return 1.f / (1.f + __expf(-x));
}
static __device__ __forceinline__ float tanh_f(float x) {
    return 2.f / (1.f + __expf(-2.f * x)) - 1.f;
}

// ---- pack weights: Wp[n][k] bf16, n in [0,4096), k<512 from Kw, else Rw
__global__ __launch_bounds__(256) void pack_w(const float* __restrict__ Kw,
                                              const float* __restrict__ Rw,
                                              unsigned short* __restrict__ Wp) {
    __shared__ float tile[32][33];
    int nt = blockIdx.x * 32;
    int kt = blockIdx.y * 32;
    int tx = threadIdx.x, ty = threadIdx.y;  // 32 x 8
#pragma unroll
    for (int i = 0; i < 32; i += 8) {
        int k = kt + ty + i;
        int n = nt + tx;
        float v = (k < Dq) ? Kw[(size_t)k * N4H + n] : Rw[(size_t)(k - Dq) * N4H + n];
        tile[ty + i][tx] = v;
    }
    __syncthreads();
#pragma unroll
    for (int i = 0; i < 32; i += 8) {
        int n = nt + ty + i;
        int k = kt + tx;
        Wp[(size_t)n * KTOT + k] = f2bf(tile[tx][ty + i]);
    }
}

// ---- cast + transpose input to bf16 [T][B][D]
__global__ __launch_bounds__(256) void pack_x(const float* __restrict__ X,
                                              unsigned short* __restrict__ Xb) {
    int gid = blockIdx.x * 256 + threadIdx.x;  // 2,097,152 chunks of 8
    int dc = gid & 63;
    int t = (gid >> 6) & 255;
    int b = gid >> 14;
    const float* src = X + ((size_t)b * Tq + t) * Dq + dc * 8;
    float4 v0 = *(const float4*)src;
    float4 v1 = *(const float4*)(src + 4);
    bf16x8 r;
    r[0] = (short)f2bf(v0.x); r[1] = (short)f2bf(v0.y);
    r[2] = (short)f2bf(v0.z); r[3] = (short)f2bf(v0.w);
    r[4] = (short)f2bf(v1.x); r[5] = (short)f2bf(v1.y);
    r[6] = (short)f2bf(v1.z); r[7] = (short)f2bf(v1.w);
    *(bf16x8*)(Xb + ((size_t)t * Bq + b) * Dq + dc * 8) = r;
}

// ---- zero h buffer 0 + barrier state
__global__ __launch_bounds__(256) void init_ws(unsigned short* __restrict__ Hb,
                                               unsigned* __restrict__ bar) {
    int i = blockIdx.x * 256 + threadIdx.x;  // 131072
    Hb[i] = 0;
    if (i < 2048) bar[i] = 0;
}

// barrier word layout (u32 indices, 128B-separated lines):
//   xcd_cnt[x] @ x*32, topo[x] @ 512+x*32, gbar @ 1024, xflag[x] @ 1280+x*32
//
// lstm: 128 wgs x 1024 threads. wg owns 8 hidden units (32 gate-cols), all 128 rows.
// 16 waves = (rg in [0,4): rows 32rg..32rg+32) x (kq in [0,4): K-quarter).
// Partial accs reduced via LDS; kq0 does epilogue. Weights in LDS, c in registers.
__global__ __launch_bounds__(NTHR, 1) void lstm_persist(
    const unsigned short* __restrict__ Wp,
    const unsigned short* __restrict__ Xb,
    const float* __restrict__ bias,
    unsigned short* __restrict__ Hb,
    const float* __restrict__ dw,
    const float* __restrict__ db,
    float* __restrict__ out,
    unsigned* __restrict__ bar) {
    extern __shared__ unsigned short Wl[];  // 32*LDW ushorts (98,816 B) + 49,152 B redbuf
    float* redbuf = (float*)(Wl + 32 * LDW);
    __shared__ float red[16];
    __shared__ int s_topo[3];  // myxcd, mytot, nxcd

    const int wg = blockIdx.x;
    const int hs0 = wg * 8;
    const int tid = threadIdx.x;
    const int wave = tid >> 6;
    const int lane = tid & 63;
    const int rg = wave & 3;    // row group: rows [32rg, 32rg+32)
    const int kq = wave >> 2;   // K quarter
    const int rowb = rg * 32;
    const int c16 = lane & 15;
    const int kg = lane >> 4;

    // ---- startup: discover physical XCD topology (pure relaxed atomics)
    if (tid == 0) {
        int xcd;
        asm volatile("s_getreg_b32 %0, hwreg(HW_REG_XCC_ID)" : "=s"(xcd));
        xcd &= 15;
        __hip_atomic_fetch_add(&bar[512 + xcd * 32], 1u, __ATOMIC_RELAXED, __HIP_MEMORY_SCOPE_AGENT);
        for (;;) {
            unsigned sum = 0;
            for (int i = 0; i < 16; ++i)
                sum += __hip_atomic_load(&bar[512 + i * 32], __ATOMIC_RELAXED, __HIP_MEMORY_SCOPE_AGENT);
            if (sum == NWG) break;
            __builtin_amdgcn_s_sleep(2);
        }
        int nx = 0, tot = 0;
        for (int i = 0; i < 16; ++i) {
            unsigned v = __hip_atomic_load(&bar[512 + i * 32], __ATOMIC_RELAXED, __HIP_MEMORY_SCOPE_AGENT);
            if (v) nx++;
            if (i == xcd) tot = (int)v;
        }
        s_topo[0] = xcd;
        s_topo[1] = tot;
        s_topo[2] = nx;
    }

    // load this wg's 32 weight columns into LDS (once)
    for (int c = tid; c < 32 * 192; c += NTHR) {
        int lc = c / 192;   // local col: q*8+u
        int pos = c % 192;  // bf16x8 chunk within row
        int q = lc >> 3, u = lc & 7;
        bf16x8 v = *(const bf16x8*)(Wp + (size_t)(q * Hq + hs0 + u) * KTOT + pos * 8);
        *(bf16x8*)(&Wl[lc * LDW + pos * 8]) = v;
    }

    const int col0 = (c16 >> 3) * Hq + hs0 + (c16 & 7);
    const int col1 = ((c16 >> 3) + 2) * Hq + hs0 + (c16 & 7);
    const float bias0 = bias[col0];
    const float bias1 = bias[col1];
    const bool hi = (c16 & 8) != 0;
    const int j = hs0 + (c16 & 7);
    const int arow0 = rowb + c16;
    const int arow1 = arow0 + 16;
    const int wl0 = c16 * LDW + kg * 8;
    const int wl1 = (16 + c16) * LDW + kg * 8;
    // this wave's K slices
    const int xoff = kq * 128 + kg * 8;        // x K-quarter (of 512)
    const int hoff = kq * 256 + kg * 8;        // h K-quarter (of 1024)
    const int rbase = (((kq - 1) * 4 + rg) * 64 + lane) * 16;  // redbuf slot (kq>=1)
    float* myred = &redbuf[((kq ? rbase : 0))];

    float creg[8];
#pragma unroll
    for (int i = 0; i < 8; ++i) creg[i] = 0.f;

    __syncthreads();
    const int myxcd = s_topo[0];
    const unsigned mytot = (unsigned)s_topo[1];
    const unsigned nxcd = (unsigned)s_topo[2];

    // x-part partial accumulators for step 0 (this wave's K-quarter)
    f32x4 xa00 = {0.f, 0.f, 0.f, 0.f};
    f32x4 xa01 = {0.f, 0.f, 0.f, 0.f};
    f32x4 xa10 = {0.f, 0.f, 0.f, 0.f};
    f32x4 xa11 = {0.f, 0.f, 0.f, 0.f};
    {
        const unsigned short* xr0 = Xb + (size_t)arow0 * Dq + xoff;
        const unsigned short* xr1 = Xb + (size_t)arow1 * Dq + xoff;
#pragma unroll
        for (int kc = 0; kc < 4; ++kc) {
            bf16x8 a0 = *(const bf16x8*)(xr0 + kc * 32);
            bf16x8 a1 = *(const bf16x8*)(xr1 + kc * 32);
            bf16x8 b0 = *(const bf16x8*)(&Wl[wl0 + xoff + kc * 32 - kg * 8 + kg * 8]);
            bf16x8 b1 = *(const bf16x8*)(&Wl[wl1 + xoff + kc * 32 - kg * 8 + kg * 8]);
            xa00 = __builtin_amdgcn_mfma_f32_16x16x32_bf16(a0, b0, xa00, 0, 0, 0);
            xa01 = __builtin_amdgcn_mfma_f32_16x16x32_bf16(a0, b1, xa01, 0, 0, 0);
            xa10 = __builtin_amdgcn_mfma_f32_16x16x32_bf16(a1, b0, xa10, 0, 0, 0);
            xa11 = __builtin_amdgcn_mfma_f32_16x16x32_bf16(a1, b1, xa11, 0, 0, 0);
        }
    }

    for (int t = 0; t < Tq; ++t) {
        const unsigned short* Hcur = Hb + (size_t)(t & 1) * (Bq * Hq);
        unsigned short* Hnxt = Hb + (size_t)((t + 1) & 1) * (Bq * Hq);

        const unsigned short* hr0 = Hcur + (size_t)arow0 * Hq + hoff;
        const unsigned short* hr1 = Hcur + (size_t)arow1 * Hq + hoff;

        f32x4 acc00 = xa00, acc01 = xa01, acc10 = xa10, acc11 = xa11;

        // h-part GEMM over this wave's K-quarter (8 kc iterations)
#pragma unroll
        for (int kc = 0; kc < 8; ++kc) {
            bf16x8 a0 = *(const bf16x8*)(hr0 + kc * 32);
            bf16x8 a1 = *(const bf16x8*)(hr1 + kc * 32);
            bf16x8 b0 = *(const bf16x8*)(&Wl[wl0 + 512 + kq * 256 + kc * 32]);
            bf16x8 b1 = *(const bf16x8*)(&Wl[wl1 + 512 + kq * 256 + kc * 32]);
            acc00 = __builtin_amdgcn_mfma_f32_16x16x32_bf16(a0, b0, acc00, 0, 0, 0);
            acc01 = __builtin_amdgcn_mfma_f32_16x16x32_bf16(a0, b1, acc01, 0, 0, 0);
            acc10 = __builtin_amdgcn_mfma_f32_16x16x32_bf16(a1, b0, acc10, 0, 0, 0);
            acc11 = __builtin_amdgcn_mfma_f32_16x16x32_bf16(a1, b1, acc11, 0, 0, 0);
        }

        // partial-acc write (kq>=1)
        if (kq) {
            *(f32x4*)&myred[0] = acc00;
            *(f32x4*)&myred[4] = acc01;
            *(f32x4*)&myred[8] = acc10;
            *(f32x4*)&myred[12] = acc11;
        }
        __syncthreads();  // (A) partials visible

        if (kq == 0) {
            // reduce + epilogue + h store
#pragma unroll
            for (int kqi = 1; kqi < 4; ++kqi) {
                const float* rb = &redbuf[(((kqi - 1) * 4 + rg) * 64 + lane) * 16];
                acc00 += *(const f32x4*)&rb[0];
                acc01 += *(const f32x4*)&rb[4];
                acc10 += *(const f32x4*)&rb[8];
                acc11 += *(const f32x4*)&rb[12];
            }
#pragma unroll
            for (int m = 0; m < 2; ++m) {
                f32x4 z0 = m ? acc10 : acc00;
                f32x4 z1 = m ? acc11 : acc01;
#pragma unroll
                for (int r = 0; r < 4; ++r) {
                    float za = z0[r] + bias0;
                    float zb = z1[r] + bias1;
                    float pa = __shfl_xor(za, 8, 64);
                    float pb = __shfl_xor(zb, 8, 64);
                    float zi = hi ? pa : za;
                    float zf = hi ? za : pa;
                    float zg = hi ? pb : zb;
                    float zo = hi ? zb : pb;
                    float gi = sigm(zi);
                    float gf = sigm(zf);
                    float go = sigm(zo);
                    float gg = tanh_f(zg);
                    float cn = gf * creg[m * 4 + r] + gi * gg;
                    creg[m * 4 + r] = cn;
                    float hn = go * tanh_f(cn);
                    if (!hi) {
                        int b = rowb + m * 16 + kg * 4 + r;
                        Hnxt[(size_t)b * Hq + j] = f2bf(hn);
                    }
                }
            }
        } else if (t + 1 < Tq) {
            // overlap with kq0's epilogue: x-part GEMM for step t+1
            const unsigned short* xr0 = Xb + ((size_t)(t + 1) * Bq + arow0) * Dq + xoff;
            const unsigned short* xr1 = Xb + ((size_t)(t + 1) * Bq + arow1) * Dq + xoff;
            xa00 = (f32x4){0.f, 0.f, 0.f, 0.f};
            xa01 = (f32x4){0.f, 0.f, 0.f, 0.f};
            xa10 = (f32x4){0.f, 0.f, 0.f, 0.f};
            xa11 = (f32x4){0.f, 0.f, 0.f, 0.f};
#pragma unroll
            for (int kc = 0; kc < 4; ++kc) {
                bf16x8 a0 = *(const bf16x8*)(xr0 + kc * 32);
                bf16x8 a1 = *(const bf16x8*)(xr1 + kc * 32);
                bf16x8 b0 = *(const bf16x8*)(&Wl[wl0 + kq * 128 + kc * 32]);
                bf16x8 b1 = *(const bf16x8*)(&Wl[wl1 + kq * 128 + kc * 32]);
                xa00 = __builtin_amdgcn_mfma_f32_16x16x32_bf16(a0, b0, xa00, 0, 0, 0);
                xa01 = __builtin_amdgcn_mfma_f32_16x16x32_bf16(a0, b1, xa01, 0, 0, 0);
                xa10 = __builtin_amdgcn_mfma_f32_16x16x32_bf16(a1, b0, xa10, 0, 0, 0);
                xa11 = __builtin_amdgcn_mfma_f32_16x16x32_bf16(a1, b1, xa11, 0, 0, 0);
            }
        }

        __syncthreads();  // (B) h stores drained (per-wave vmcnt in syncthreads)

        // ---- arrive: per-XCD counter; last-on-XCD: release wbl2 + global add;
        // last globally (via return value): fan-out to per-XCD flag lines.
        if (tid == 0) {
            unsigned old = __hip_atomic_fetch_add(&bar[myxcd * 32], 1u,
                                                  __ATOMIC_RELAXED, __HIP_MEMORY_SCOPE_AGENT);
            if (old == (unsigned)(t + 1) * mytot - 1u) {
                __builtin_amdgcn_fence(__ATOMIC_RELEASE, "agent");
                unsigned gold = __hip_atomic_fetch_add(&bar[1024], 1u,
                                                       __ATOMIC_RELAXED, __HIP_MEMORY_SCOPE_AGENT);
                if (gold == (unsigned)(t + 1) * nxcd - 1u) {
#pragma unroll
                    for (int x = 0; x < 16; ++x)
                        __hip_atomic_store(&bar[1280 + x * 32], (unsigned)(t + 1),
                                           __ATOMIC_RELAXED, __HIP_MEMORY_SCOPE_AGENT);
                }
            }
        }

        // kq0 waves: x-part GEMM for t+1 (overlaps barrier wait)
        if (kq == 0 && t + 1 < Tq) {
            const unsigned short* xr0 = Xb + ((size_t)(t + 1) * Bq + arow0) * Dq + xoff;
            const unsigned short* xr1 = Xb + ((size_t)(t + 1) * Bq + arow1) * Dq + xoff;
            xa00 = (f32x4){0.f, 0.f, 0.f, 0.f};
            xa01 = (f32x4){0.f, 0.f, 0.f, 0.f};
            xa10 = (f32x4){0.f, 0.f, 0.f, 0.f};
            xa11 = (f32x4){0.f, 0.f, 0.f, 0.f};
#pragma unroll
            for (int kc = 0; kc < 4; ++kc) {
                bf16x8 a0 = *(const bf16x8*)(xr0 + kc * 32);
                bf16x8 a1 = *(const bf16x8*)(xr1 + kc * 32);
                bf16x8 b0 = *(const bf16x8*)(&Wl[wl0 + kc * 32]);  // kq==0
                bf16x8 b1 = *(const bf16x8*)(&Wl[wl1 + kc * 32]);
                xa00 = __builtin_amdgcn_mfma_f32_16x16x32_bf16(a0, b0, xa00, 0, 0, 0);
                xa01 = __builtin_amdgcn_mfma_f32_16x16x32_bf16(a0, b1, xa01, 0, 0, 0);
                xa10 = __builtin_amdgcn_mfma_f32_16x16x32_bf16(a1, b0, xa10, 0, 0, 0);
                xa11 = __builtin_amdgcn_mfma_f32_16x16x32_bf16(a1, b1, xa11, 0, 0, 0);
            }
        }

        // ---- wait: poll only this XCD's flag line, then one acquire inv per wg
        if (tid == 0) {
            while (__hip_atomic_load(&bar[1280 + myxcd * 32], __ATOMIC_RELAXED,
                                     __HIP_MEMORY_SCOPE_AGENT) < (unsigned)(t + 1)) {
                __builtin_amdgcn_s_sleep(4);
            }
            asm volatile("" ::: "memory");
            __builtin_amdgcn_fence(__ATOMIC_ACQUIRE, "agent");
        }
        __syncthreads();  // (C)
    }

    // dense head: wg handles batch row b = wg; final h in buffer 0 (t=256 even)
    {
        const unsigned short* hl = Hb + (size_t)wg * Hq;
        float s = bf2f(hl[tid]) * dw[tid];  // Hq == NTHR
#pragma unroll
        for (int off = 32; off > 0; off >>= 1) s += __shfl_down(s, off, 64);
        if (lane == 0) red[wave] = s;
        __syncthreads();
        if (tid == 0) {
            float tot = db[0];
#pragma unroll
            for (int wv = 0; wv < 16; ++wv) tot += red[wv];
            out[wg] = 1.f / (1.f + __expf(-tot));
        }
    }
}

extern "C" void kernel_launch(void* const* d_in, const int* in_sizes, int n_in,
                              void* d_out, int out_size, void* d_ws, size_t ws_size,
                              hipStream_t stream) {
    const float* X = (const float*)d_in[0];
    const float* Kw = (const float*)d_in[1];
    const float* Rw = (const float*)d_in[2];
    const float* bias = (const float*)d_in[3];
    const float* dw = (const float*)d_in[4];
    const float* db = (const float*)d_in[5];
    float* out = (float*)d_out;
    char* ws = (char*)d_ws;

    // workspace layout:
    //   Wp  bf16 [4096][1536]     @ 0          (12,582,912)
    //   Xb  bf16 [256][128][512]  @ 12,582,912 (33,554,432)   [T][B][D]
    //   Hb  bf16 [2][128][1024]   @ 46,137,344 (524,288)
    //   bar u32  [2048]           @ 46,661,632 (8,192)
    unsigned short* Wp = (unsigned short*)(ws);
    unsigned short* Xb = (unsigned short*)(ws + 12582912);
    unsigned short* Hb = (unsigned short*)(ws + 46137344);
    unsigned* bar = (unsigned*)(ws + 46661632);

    pack_w<<<dim3(128, 48), dim3(32, 8), 0, stream>>>(Kw, Rw, Wp);
    pack_x<<<8192, 256, 0, stream>>>(X, Xb);
    init_ws<<<512, 256, 0, stream>>>(Hb, bar);

    size_t lds_bytes = (size_t)32 * LDW * sizeof(unsigned short) + 49152;  // 148,  -> 147,968
    lstm_persist<<<NWG, NTHR, lds_bytes, stream>>>(Wp, Xb, bias, Hb, dw, db, out, bar);
}

// Round 9
// 3911.270 us; speedup vs baseline: 1.4377x; 1.0448x over previous
//
#include <hip/hip_runtime.h>

#define Bq 128
#define Tq 256
#define Dq 512
#define Hq 1024
#define N4H 4096
#define KTOT 1536
#define LDW 1544   // LDS row stride in ushorts
#define NWG 128
#define NTHR 1024
#define BHq (Bq * Hq)      // one h buffer: 131072 elems
#define NHBUF (Tq + 1)     // rotating h buffers: h_0 .. h_256, each address written/read once

typedef __attribute__((ext_vector_type(8))) short bf16x8;
typedef __attribute__((ext_vector_type(4))) float f32x4;

static __device__ __forceinline__ unsigned short f2bf(float x) {
    unsigned int u = __builtin_bit_cast(unsigned int, x);
    u = (u + 0x7FFFu + ((u >> 16) & 1u)) >> 16;
    return (unsigned short)u;
}
static __device__ __forceinline__ float bf2f(unsigned short h) {
    unsigned int u = ((unsigned int)h) << 16;
    return __builtin_bit_cast(float, u);
}
static __device__ __forceinline__ float sigm(float x) {
    return 1.f / (1.f + __expf(-x));
}
static __device__ __forceinline__ float tanh_f(float x) {
    return 2.f / (1.f + __expf(-2.f * x)) - 1.f;
}

// ---- pack weights: Wp[n][k] bf16, n in [0,4096), k<512 from Kw, else Rw
__global__ __launch_bounds__(256) void pack_w(const float* __restrict__ Kw,
                                              const float* __restrict__ Rw,
                                              unsigned short* __restrict__ Wp) {
    __shared__ float tile[32][33];
    int nt = blockIdx.x * 32;
    int kt = blockIdx.y * 32;
    int tx = threadIdx.x, ty = threadIdx.y;  // 32 x 8
#pragma unroll
    for (int i = 0; i < 32; i += 8) {
        int k = kt + ty + i;
        int n = nt + tx;
        float v = (k < Dq) ? Kw[(size_t)k * N4H + n] : Rw[(size_t)(k - Dq) * N4H + n];
        tile[ty + i][tx] = v;
    }
    __syncthreads();
#pragma unroll
    for (int i = 0; i < 32; i += 8) {
        int n = nt + ty + i;
        int k = kt + tx;
        Wp[(size_t)n * KTOT + k] = f2bf(tile[tx][ty + i]);
    }
}

// ---- cast + transpose input to bf16 [T][B][D]
__global__ __launch_bounds__(256) void pack_x(const float* __restrict__ X,
                                              unsigned short* __restrict__ Xb) {
    int gid = blockIdx.x * 256 + threadIdx.x;  // 2,097,152 chunks of 8
    int dc = gid & 63;
    int t = (gid >> 6) & 255;
    int b = gid >> 14;
    const float* src = X + ((size_t)b * Tq + t) * Dq + dc * 8;
    float4 v0 = *(const float4*)src;
    float4 v1 = *(const float4*)(src + 4);
    bf16x8 r;
    r[0] = (short)f2bf(v0.x); r[1] = (short)f2bf(v0.y);
    r[2] = (short)f2bf(v0.z); r[3] = (short)f2bf(v0.w);
    r[4] = (short)f2bf(v1.x); r[5] = (short)f2bf(v1.y);
    r[6] = (short)f2bf(v1.z); r[7] = (short)f2bf(v1.w);
    *(bf16x8*)(Xb + ((size_t)t * Bq + b) * Dq + dc * 8) = r;
}

// ---- zero h buffer 0 + barrier state
__global__ __launch_bounds__(256) void init_ws(unsigned short* __restrict__ Hb,
                                               unsigned* __restrict__ bar) {
    int i = blockIdx.x * 256 + threadIdx.x;  // 131072 = buffer 0 exactly
    Hb[i] = 0;
    if (i < 2048) bar[i] = 0;
}

// barrier word layout (u32 indices, 128B-separated lines):
//   xcd_cnt[x] @ x*32, topo[x] @ 512+x*32, gbar @ 1024, xflag[x] @ 1280+x*32
//
// lstm: 128 wgs x 1024 threads. wg owns 8 hidden units (32 gate-cols), all 128 rows.
// 16 waves = (rg in [0,4): rows 32rg..32rg+32) x (kq in [0,4): K-quarter).
// ROTATING h buffers (one per timestep): consumer reads always touch fresh
// addresses -> no stale-cache hazard -> NO acquire fence anywhere. Release is
// one wbl2 per XCD per step (last arriver), proven cheap in r5.
__global__ __launch_bounds__(NTHR, 1) void lstm_persist(
    const unsigned short* __restrict__ Wp,
    const unsigned short* __restrict__ Xb,
    const float* __restrict__ bias,
    unsigned short* __restrict__ Hb,
    const float* __restrict__ dw,
    const float* __restrict__ db,
    float* __restrict__ out,
    unsigned* __restrict__ bar) {
    extern __shared__ unsigned short Wl[];  // 32*LDW ushorts (98,816 B) + 49,152 B redbuf
    float* redbuf = (float*)(Wl + 32 * LDW);
    __shared__ float red[16];
    __shared__ int s_topo[3];  // myxcd, mytot, nxcd

    const int wg = blockIdx.x;
    const int hs0 = wg * 8;
    const int tid = threadIdx.x;
    const int wave = tid >> 6;
    const int lane = tid & 63;
    const int rg = wave & 3;    // row group: rows [32rg, 32rg+32)
    const int kq = wave >> 2;   // K quarter
    const int rowb = rg * 32;
    const int c16 = lane & 15;
    const int kg = lane >> 4;

    // ---- startup: discover physical XCD topology (pure relaxed atomics)
    if (tid == 0) {
        int xcd;
        asm volatile("s_getreg_b32 %0, hwreg(HW_REG_XCC_ID)" : "=s"(xcd));
        xcd &= 15;
        __hip_atomic_fetch_add(&bar[512 + xcd * 32], 1u, __ATOMIC_RELAXED, __HIP_MEMORY_SCOPE_AGENT);
        for (;;) {
            unsigned sum = 0;
            for (int i = 0; i < 16; ++i)
                sum += __hip_atomic_load(&bar[512 + i * 32], __ATOMIC_RELAXED, __HIP_MEMORY_SCOPE_AGENT);
            if (sum == NWG) break;
            __builtin_amdgcn_s_sleep(2);
        }
        int nx = 0, tot = 0;
        for (int i = 0; i < 16; ++i) {
            unsigned v = __hip_atomic_load(&bar[512 + i * 32], __ATOMIC_RELAXED, __HIP_MEMORY_SCOPE_AGENT);
            if (v) nx++;
            if (i == xcd) tot = (int)v;
        }
        s_topo[0] = xcd;
        s_topo[1] = tot;
        s_topo[2] = nx;
    }

    // load this wg's 32 weight columns into LDS (once)
    for (int c = tid; c < 32 * 192; c += NTHR) {
        int lc = c / 192;   // local col: q*8+u
        int pos = c % 192;  // bf16x8 chunk within row
        int q = lc >> 3, u = lc & 7;
        bf16x8 v = *(const bf16x8*)(Wp + (size_t)(q * Hq + hs0 + u) * KTOT + pos * 8);
        *(bf16x8*)(&Wl[lc * LDW + pos * 8]) = v;
    }

    const int col0 = (c16 >> 3) * Hq + hs0 + (c16 & 7);
    const int col1 = ((c16 >> 3) + 2) * Hq + hs0 + (c16 & 7);
    const float bias0 = bias[col0];
    const float bias1 = bias[col1];
    const bool hi = (c16 & 8) != 0;
    const int j = hs0 + (c16 & 7);
    const int arow0 = rowb + c16;
    const int arow1 = arow0 + 16;
    const int wl0 = c16 * LDW + kg * 8;
    const int wl1 = (16 + c16) * LDW + kg * 8;
    // this wave's K slices
    const int xoff = kq * 128 + kg * 8;        // x K-quarter (of 512)
    const int hoff = kq * 256 + kg * 8;        // h K-quarter (of 1024)
    const int rbase = (((kq - 1) * 4 + rg) * 64 + lane) * 16;  // redbuf slot (kq>=1)
    float* myred = &redbuf[((kq ? rbase : 0))];

    float creg[8];
#pragma unroll
    for (int i = 0; i < 8; ++i) creg[i] = 0.f;

    __syncthreads();
    const int myxcd = s_topo[0];
    const unsigned mytot = (unsigned)s_topo[1];
    const unsigned nxcd = (unsigned)s_topo[2];

    // x-part partial accumulators for step 0 (this wave's K-quarter)
    f32x4 xa00 = {0.f, 0.f, 0.f, 0.f};
    f32x4 xa01 = {0.f, 0.f, 0.f, 0.f};
    f32x4 xa10 = {0.f, 0.f, 0.f, 0.f};
    f32x4 xa11 = {0.f, 0.f, 0.f, 0.f};
    {
        const unsigned short* xr0 = Xb + (size_t)arow0 * Dq + xoff;
        const unsigned short* xr1 = Xb + (size_t)arow1 * Dq + xoff;
#pragma unroll
        for (int kc = 0; kc < 4; ++kc) {
            bf16x8 a0 = *(const bf16x8*)(xr0 + kc * 32);
            bf16x8 a1 = *(const bf16x8*)(xr1 + kc * 32);
            bf16x8 b0 = *(const bf16x8*)(&Wl[wl0 + kq * 128 + kc * 32]);
            bf16x8 b1 = *(const bf16x8*)(&Wl[wl1 + kq * 128 + kc * 32]);
            xa00 = __builtin_amdgcn_mfma_f32_16x16x32_bf16(a0, b0, xa00, 0, 0, 0);
            xa01 = __builtin_amdgcn_mfma_f32_16x16x32_bf16(a0, b1, xa01, 0, 0, 0);
            xa10 = __builtin_amdgcn_mfma_f32_16x16x32_bf16(a1, b0, xa10, 0, 0, 0);
            xa11 = __builtin_amdgcn_mfma_f32_16x16x32_bf16(a1, b1, xa11, 0, 0, 0);
        }
    }

    for (int t = 0; t < Tq; ++t) {
        // rotating buffers: read h_t from buf[t], write h_{t+1} to buf[t+1]
        const unsigned short* Hcur = Hb + (size_t)t * BHq;
        unsigned short* Hnxt = Hb + (size_t)(t + 1) * BHq;

        const unsigned short* hr0 = Hcur + (size_t)arow0 * Hq + hoff;
        const unsigned short* hr1 = Hcur + (size_t)arow1 * Hq + hoff;

        f32x4 acc00 = xa00, acc01 = xa01, acc10 = xa10, acc11 = xa11;

        // h-part GEMM over this wave's K-quarter (8 kc iterations)
#pragma unroll
        for (int kc = 0; kc < 8; ++kc) {
            bf16x8 a0 = *(const bf16x8*)(hr0 + kc * 32);
            bf16x8 a1 = *(const bf16x8*)(hr1 + kc * 32);
            bf16x8 b0 = *(const bf16x8*)(&Wl[wl0 + 512 + kq * 256 + kc * 32]);
            bf16x8 b1 = *(const bf16x8*)(&Wl[wl1 + 512 + kq * 256 + kc * 32]);
            acc00 = __builtin_amdgcn_mfma_f32_16x16x32_bf16(a0, b0, acc00, 0, 0, 0);
            acc01 = __builtin_amdgcn_mfma_f32_16x16x32_bf16(a0, b1, acc01, 0, 0, 0);
            acc10 = __builtin_amdgcn_mfma_f32_16x16x32_bf16(a1, b0, acc10, 0, 0, 0);
            acc11 = __builtin_amdgcn_mfma_f32_16x16x32_bf16(a1, b1, acc11, 0, 0, 0);
        }

        // partial-acc write (kq>=1)
        if (kq) {
            *(f32x4*)&myred[0] = acc00;
            *(f32x4*)&myred[4] = acc01;
            *(f32x4*)&myred[8] = acc10;
            *(f32x4*)&myred[12] = acc11;
        }
        __syncthreads();  // (A) partials visible

        if (kq == 0) {
            // reduce + epilogue + h store (normal stores; wbl2 at arrive publishes)
#pragma unroll
            for (int kqi = 1; kqi < 4; ++kqi) {
                const float* rb = &redbuf[(((kqi - 1) * 4 + rg) * 64 + lane) * 16];
                acc00 += *(const f32x4*)&rb[0];
                acc01 += *(const f32x4*)&rb[4];
                acc10 += *(const f32x4*)&rb[8];
                acc11 += *(const f32x4*)&rb[12];
            }
#pragma unroll
            for (int m = 0; m < 2; ++m) {
                f32x4 z0 = m ? acc10 : acc00;
                f32x4 z1 = m ? acc11 : acc01;
#pragma unroll
                for (int r = 0; r < 4; ++r) {
                    float za = z0[r] + bias0;
                    float zb = z1[r] + bias1;
                    float pa = __shfl_xor(za, 8, 64);
                    float pb = __shfl_xor(zb, 8, 64);
                    float zi = hi ? pa : za;
                    float zf = hi ? za : pa;
                    float zg = hi ? pb : zb;
                    float zo = hi ? zb : pb;
                    float gi = sigm(zi);
                    float gf = sigm(zf);
                    float go = sigm(zo);
                    float gg = tanh_f(zg);
                    float cn = gf * creg[m * 4 + r] + gi * gg;
                    creg[m * 4 + r] = cn;
                    float hn = go * tanh_f(cn);
                    if (!hi) {
                        int b = rowb + m * 16 + kg * 4 + r;
                        Hnxt[(size_t)b * Hq + j] = f2bf(hn);
                    }
                }
            }
        } else if (t + 1 < Tq) {
            // overlap with kq0's epilogue: x-part GEMM for step t+1
            const unsigned short* xr0 = Xb + ((size_t)(t + 1) * Bq + arow0) * Dq + xoff;
            const unsigned short* xr1 = Xb + ((size_t)(t + 1) * Bq + arow1) * Dq + xoff;
            xa00 = (f32x4){0.f, 0.f, 0.f, 0.f};
            xa01 = (f32x4){0.f, 0.f, 0.f, 0.f};
            xa10 = (f32x4){0.f, 0.f, 0.f, 0.f};
            xa11 = (f32x4){0.f, 0.f, 0.f, 0.f};
#pragma unroll
            for (int kc = 0; kc < 4; ++kc) {
                bf16x8 a0 = *(const bf16x8*)(xr0 + kc * 32);
                bf16x8 a1 = *(const bf16x8*)(xr1 + kc * 32);
                bf16x8 b0 = *(const bf16x8*)(&Wl[wl0 + kq * 128 + kc * 32]);
                bf16x8 b1 = *(const bf16x8*)(&Wl[wl1 + kq * 128 + kc * 32]);
                xa00 = __builtin_amdgcn_mfma_f32_16x16x32_bf16(a0, b0, xa00, 0, 0, 0);
                xa01 = __builtin_amdgcn_mfma_f32_16x16x32_bf16(a0, b1, xa01, 0, 0, 0);
                xa10 = __builtin_amdgcn_mfma_f32_16x16x32_bf16(a1, b0, xa10, 0, 0, 0);
                xa11 = __builtin_amdgcn_mfma_f32_16x16x32_bf16(a1, b1, xa11, 0, 0, 0);
            }
        }

        __syncthreads();  // (B) all waves' h stores drained (vmcnt in syncthreads)

        // ---- arrive: per-XCD counter; last-on-XCD: release wbl2 (publishes the
        // whole XCD's h stores) + global add; last globally: flag fan-out.
        if (tid == 0) {
            unsigned old = __hip_atomic_fetch_add(&bar[myxcd * 32], 1u,
                                                  __ATOMIC_RELAXED, __HIP_MEMORY_SCOPE_AGENT);
            if (old == (unsigned)(t + 1) * mytot - 1u) {
                __builtin_amdgcn_fence(__ATOMIC_RELEASE, "agent");
                unsigned gold = __hip_atomic_fetch_add(&bar[1024], 1u,
                                                       __ATOMIC_RELAXED, __HIP_MEMORY_SCOPE_AGENT);
                if (gold == (unsigned)(t + 1) * nxcd - 1u) {
#pragma unroll
                    for (int x = 0; x < 16; ++x)
                        __hip_atomic_store(&bar[1280 + x * 32], (unsigned)(t + 1),
                                           __ATOMIC_RELAXED, __HIP_MEMORY_SCOPE_AGENT);
                }
            }
        }

        // kq0 waves: x-part GEMM for t+1 (overlaps barrier wait)
        if (kq == 0 && t + 1 < Tq) {
            const unsigned short* xr0 = Xb + ((size_t)(t + 1) * Bq + arow0) * Dq + xoff;
            const unsigned short* xr1 = Xb + ((size_t)(t + 1) * Bq + arow1) * Dq + xoff;
            xa00 = (f32x4){0.f, 0.f, 0.f, 0.f};
            xa01 = (f32x4){0.f, 0.f, 0.f, 0.f};
            xa10 = (f32x4){0.f, 0.f, 0.f, 0.f};
            xa11 = (f32x4){0.f, 0.f, 0.f, 0.f};
#pragma unroll
            for (int kc = 0; kc < 4; ++kc) {
                bf16x8 a0 = *(const bf16x8*)(xr0 + kc * 32);
                bf16x8 a1 = *(const bf16x8*)(xr1 + kc * 32);
                bf16x8 b0 = *(const bf16x8*)(&Wl[wl0 + kc * 32]);  // kq==0
                bf16x8 b1 = *(const bf16x8*)(&Wl[wl1 + kc * 32]);
                xa00 = __builtin_amdgcn_mfma_f32_16x16x32_bf16(a0, b0, xa00, 0, 0, 0);
                xa01 = __builtin_amdgcn_mfma_f32_16x16x32_bf16(a0, b1, xa01, 0, 0, 0);
                xa10 = __builtin_amdgcn_mfma_f32_16x16x32_bf16(a1, b0, xa10, 0, 0, 0);
                xa11 = __builtin_amdgcn_mfma_f32_16x16x32_bf16(a1, b1, xa11, 0, 0, 0);
            }
        }

        // ---- wait: poll only this XCD's flag line. NO acquire fence — the
        // h_t+1 addresses have never been cached by this CU (rotating buffers),
        // so there is nothing stale to invalidate.
        if (tid == 0) {
            while (__hip_atomic_load(&bar[1280 + myxcd * 32], __ATOMIC_RELAXED,
                                     __HIP_MEMORY_SCOPE_AGENT) < (unsigned)(t + 1)) {
                __builtin_amdgcn_s_sleep(4);
            }
            asm volatile("" ::: "memory");
        }
        __syncthreads();  // (C)
    }

    // dense head: wg handles batch row b = wg; final h is buffer Tq (=256)
    {
        const unsigned short* hl = Hb + (size_t)Tq * BHq + (size_t)wg * Hq;
        float s = bf2f(hl[tid]) * dw[tid];  // Hq == NTHR
#pragma unroll
        for (int off = 32; off > 0; off >>= 1) s += __shfl_down(s, off, 64);
        if (lane == 0) red[wave] = s;
        __syncthreads();
        if (tid == 0) {
            float tot = db[0];
#pragma unroll
            for (int wv = 0; wv < 16; ++wv) tot += red[wv];
            out[wg] = 1.f / (1.f + __expf(-tot));
        }
    }
}

extern "C" void kernel_launch(void* const* d_in, const int* in_sizes, int n_in,
                              void* d_out, int out_size, void* d_ws, size_t ws_size,
                              hipStream_t stream) {
    const float* X = (const float*)d_in[0];
    const float* Kw = (const float*)d_in[1];
    const float* Rw = (const float*)d_in[2];
    const float* bias = (const float*)d_in[3];
    const float* dw = (const float*)d_in[4];
    const float* db = (const float*)d_in[5];
    float* out = (float*)d_out;
    char* ws = (char*)d_ws;

    // workspace layout:
    //   Wp  bf16 [4096][1536]       @ 0          (12,582,912)
    //   Xb  bf16 [256][128][512]    @ 12,582,912 (33,554,432)   [T][B][D]
    //   Hb  bf16 [257][128][1024]   @ 46,137,344 (67,371,008)   rotating
    //   bar u32  [2048]             @ 113,508,352 (8,192)       total ~113.5 MB
    unsigned short* Wp = (unsigned short*)(ws);
    unsigned short* Xb = (unsigned short*)(ws + 12582912);
    unsigned short* Hb = (unsigned short*)(ws + 46137344);
    unsigned* bar = (unsigned*)(ws + 113508352);

    pack_w<<<dim3(128, 48), dim3(32, 8), 0, stream>>>(Kw, Rw, Wp);
    pack_x<<<8192, 256, 0, stream>>>(X, Xb);
    init_ws<<<512, 256, 0, stream>>>(Hb, bar);

    size_t lds_bytes = (size_t)32 * LDW * sizeof(unsigned short) + 49152;  // 147,968
    lstm_persist<<<NWG, NTHR, lds_bytes, stream>>>(Wp, Xb, bias, Hb, dw, db, out, bar);
}